// Round 12
// baseline (484.981 us; speedup 1.0000x reference)
//
#include <hip/hip_runtime.h>
#include <math.h>

#define N_NODES 100000
#define N_EDGES 1600000
#define NBUCKET 782            // ceil(N_NODES/128), 128 nodes per bucket
#define EB      256            // edge-blocks for hist/scatter
#define EPB     6250           // edges per block (EB*EPB == N_EDGES)

typedef __attribute__((ext_vector_type(8))) __bf16 bf16x8;
typedef __attribute__((ext_vector_type(4))) float  f32x4;

// ---------------- bf16 helpers (manual, RNE) ----------------

static __device__ __forceinline__ unsigned short f2bf(float f) {
    unsigned int u = __float_as_uint(f);
    unsigned int r = (u + 0x7FFFu + ((u >> 16) & 1u)) >> 16;
    return (unsigned short)r;
}
static __device__ __forceinline__ float bf2f(unsigned short h) {
    return __uint_as_float(((unsigned int)h) << 16);
}

// All three weights at once: Wt3[l][n][k] = bf16(W_l[k][n])
__global__ void wconv3_kernel(const float* __restrict__ W0, const float* __restrict__ W1,
                              const float* __restrict__ W2, unsigned short* __restrict__ Wt3) {
    int b = blockIdx.x;            // 0..383
    int l = b >> 7;                // 0..2
    int n = b & 127;
    int k = threadIdx.x;
    const float* W = (l == 0) ? W0 : (l == 1) ? W1 : W2;
    Wt3[l * 16384 + n * 128 + k] = f2bf(W[k * 128 + n]);
}

// ---------------- CSR build: contention-free counting sort ----------------
// Record pack: src in bits 0..16, (dst&127) in bits 20..26.

__global__ __launch_bounds__(256) void hist_kernel(const int* __restrict__ dst,
                                                   int* __restrict__ hist /*[EB][NBUCKET]*/) {
    __shared__ int h[NBUCKET];
    int tid = threadIdx.x;
    for (int b = tid; b < NBUCKET; b += 256) h[b] = 0;
    __syncthreads();
    int base = blockIdx.x * EPB;
    for (int i = tid; i < EPB; i += 256)
        atomicAdd(&h[dst[base + i] >> 7], 1);
    __syncthreads();
    int* hrow = hist + (size_t)blockIdx.x * NBUCKET;
    for (int b = tid; b < NBUCKET; b += 256) hrow[b] = h[b];
}

__global__ __launch_bounds__(256) void scan_hist_kernel(const int* __restrict__ hist,
                                                        int* __restrict__ blkoffT,
                                                        int* __restrict__ btotal) {
    __shared__ int s[256];
    int b = blockIdx.x;
    int k = threadIdx.x;
    int v = hist[(size_t)k * NBUCKET + b];
    s[k] = v;
    __syncthreads();
    for (int off = 1; off < 256; off <<= 1) {
        int t = 0;
        if (k >= off) t = s[k - off];
        __syncthreads();
        s[k] += t;
        __syncthreads();
    }
    blkoffT[(size_t)b * 256 + k] = s[k] - v;
    if (k == 255) btotal[b] = s[255];
}

// Inline exclusive scan of btotal[0..NBUCKET) into bs_l[0..NBUCKET] (LDS).
// Requires 256 threads; cs is caller-provided LDS scratch.
static __device__ __forceinline__ void scan_btotal_lds(const int* __restrict__ btotal,
                                                       int* bs_l, int* cs) {
    int tid = threadIdx.x;
    int base = tid * 4;
    int v[4];
    int sum = 0;
#pragma unroll
    for (int q = 0; q < 4; q++) {
        int idx = base + q;
        v[q] = (idx < NBUCKET) ? btotal[idx] : 0;
        sum += v[q];
    }
    cs[tid] = sum;
    __syncthreads();
    for (int off = 1; off < 256; off <<= 1) {
        int t = 0;
        if (tid >= off) t = cs[tid - off];
        __syncthreads();
        cs[tid] += t;
        __syncthreads();
    }
    int run = cs[tid] - sum;
#pragma unroll
    for (int q = 0; q < 4; q++) {
        int idx = base + q;
        if (idx < NBUCKET + 1) bs_l[idx] = run;
        run += v[q];
    }
    __syncthreads();
}

__global__ __launch_bounds__(256) void scatter_kernel(const int* __restrict__ src,
                                                      const int* __restrict__ dst,
                                                      const int* __restrict__ blkoffT,
                                                      const int* __restrict__ btotal,
                                                      int* __restrict__ pairs) {
    __shared__ int cur[NBUCKET];
    __shared__ int bs_l[NBUCKET + 2];
    __shared__ int cs[256];
    int tid = threadIdx.x;
    scan_btotal_lds(btotal, bs_l, cs);
    for (int b = tid; b < NBUCKET; b += 256)
        cur[b] = bs_l[b] + blkoffT[(size_t)b * 256 + blockIdx.x];
    __syncthreads();
    int base = blockIdx.x * EPB;
    for (int i = tid; i < EPB; i += 256) {
        int d = dst[base + i];
        int s = src[base + i];
        int pos = atomicAdd(&cur[d >> 7], 1);
        pairs[pos] = s | ((d & 127) << 20);
    }
}

__global__ __launch_bounds__(256) void build_csr_kernel(const int* __restrict__ pairs,
                                                        const int* __restrict__ btotal,
                                                        int* __restrict__ rowstart,
                                                        int* __restrict__ counts,
                                                        float* __restrict__ dis,
                                                        int* __restrict__ csr_src) {
    __shared__ int bs_l[NBUCKET + 2];
    __shared__ int cs[256];
    __shared__ int lcnt[128];
    __shared__ int lsc[128];
    __shared__ int lcur[128];
    int tid = threadIdx.x;
    int b = blockIdx.x;
    int node_base = b * 128;
    scan_btotal_lds(btotal, bs_l, cs);
    if (tid < 128) lcnt[tid] = 0;
    __syncthreads();
    int rs = bs_l[b];
    int re = bs_l[b + 1];
    for (int e = rs + tid; e < re; e += 256)
        atomicAdd(&lcnt[pairs[e] >> 20], 1);
    __syncthreads();
    if (tid < 128) lsc[tid] = lcnt[tid];
    __syncthreads();
    for (int off = 1; off < 128; off <<= 1) {
        int t = 0;
        if (tid < 128 && tid >= off) t = lsc[tid - off];
        __syncthreads();
        if (tid < 128) lsc[tid] += t;
        __syncthreads();
    }
    if (tid < 128) {
        int node = node_base + tid;
        if (node < N_NODES) {
            int startg = rs + lsc[tid] - lcnt[tid];
            rowstart[node] = startg;
            counts[node]   = lcnt[tid];
            dis[node]      = rsqrtf((float)(lcnt[tid] + 1));
            lcur[tid]      = startg;
        }
    }
    __syncthreads();
    for (int e = rs + tid; e < re; e += 256) {
        int v = pairs[e];
        int pos = atomicAdd(&lcur[v >> 20], 1);
        csr_src[pos] = v & 0xFFFFF;
    }
}

// ---------------- MFMA GEMM (no LDS, 64-row blocks): Yb = (X @ W) * dis[row] ----------------
// Grid 1563 blocks (6.1/CU, ~6 waves/SIMD for latency hiding; r10's 782 gave only ~3).
// Each wave: one 16-row A-fragment x 8 col-tiles, acc = 32 VGPR.
// Fragment layouts (mfma_f32_16x16x32_bf16):
//   A: row = lane&15, k = (lane>>4)*8 + j;  B: col = lane&15, same k
//   D: col = lane&15, row = (lane>>4)*4 + reg     [m89-verified, r8/r10-passed]

template <bool FP32IN>
__global__ __launch_bounds__(256) void gemm_mfma_kernel(const void* __restrict__ Xin,
                                                        const unsigned short* __restrict__ Wt,
                                                        const float* __restrict__ dis,
                                                        unsigned short* __restrict__ Yb) {
    int tid = threadIdx.x;
    int rowBase = blockIdx.x * 64;
    int lane = tid & 63;
    int wv_  = tid >> 6;       // wave 0..3 -> rows wv_*16..+16
    int lr   = lane & 15;
    int loct = lane >> 4;

    const float*          Xf = (const float*)Xin;
    const unsigned short* Xb = (const unsigned short*)Xin;

    f32x4 acc[8];
#pragma unroll
    for (int b = 0; b < 8; b++) acc[b] = (f32x4){0.f, 0.f, 0.f, 0.f};

    int arow = rowBase + wv_ * 16 + lr;

#pragma unroll
    for (int s = 0; s < 4; s++) {
        int kb = s * 32 + loct * 8;
        bf16x8 afr;
        if (arow < N_NODES) {
            if (FP32IN) {
                float4 v0 = *(const float4*)&Xf[(size_t)arow * 128 + kb];
                float4 v1 = *(const float4*)&Xf[(size_t)arow * 128 + kb + 4];
                union { unsigned short u[8]; bf16x8 v; } cv;
                cv.u[0] = f2bf(v0.x); cv.u[1] = f2bf(v0.y);
                cv.u[2] = f2bf(v0.z); cv.u[3] = f2bf(v0.w);
                cv.u[4] = f2bf(v1.x); cv.u[5] = f2bf(v1.y);
                cv.u[6] = f2bf(v1.z); cv.u[7] = f2bf(v1.w);
                afr = cv.v;
            } else {
                afr = *(const bf16x8*)&Xb[(size_t)arow * 128 + kb];
            }
        } else {
            union { unsigned short u[8]; bf16x8 v; } z;
#pragma unroll
            for (int j = 0; j < 8; j++) z.u[j] = 0;
            afr = z.v;
        }
#pragma unroll
        for (int tc = 0; tc < 8; tc++) {
            int col = tc * 16 + lr;
            bf16x8 bfr = *(const bf16x8*)&Wt[(size_t)col * 128 + kb];
            acc[tc] = __builtin_amdgcn_mfma_f32_16x16x32_bf16(afr, bfr, acc[tc], 0, 0, 0);
        }
    }

    // epilogue: scale by dis, store bf16
    int rbase = rowBase + wv_ * 16 + loct * 4;
    float sc[4];
#pragma unroll
    for (int r = 0; r < 4; r++)
        sc[r] = (rbase + r < N_NODES) ? dis[rbase + r] : 0.f;
#pragma unroll
    for (int tc = 0; tc < 8; tc++) {
        int col = tc * 16 + lr;
#pragma unroll
        for (int r = 0; r < 4; r++) {
            int row = rbase + r;
            if (row < N_NODES)
                Yb[(size_t)row * 128 + col] = f2bf(acc[tc][r] * sc[r]);
        }
    }
}

// ---------------- Aggregation over bf16 rows, bf16 output ----------------
// out[i] = relu( b + dis[i] * (Hs[i] + sum_{e:dst=i} Hs[src]) )   (Hs pre-scaled by dis)

__global__ __launch_bounds__(256) void aggregate_kernel(const unsigned short* __restrict__ Hs,
                                                        const float* __restrict__ dis,
                                                        const int* __restrict__ rowstart,
                                                        const int* __restrict__ counts,
                                                        const int* __restrict__ csr_src,
                                                        const float* __restrict__ bias,
                                                        unsigned int* __restrict__ OutU) {
    int node = blockIdx.x * 4 + (threadIdx.x >> 6);
    node = __builtin_amdgcn_readfirstlane(node);   // wave-uniform -> scalar loads
    int lane = threadIdx.x & 63;
    if (node >= N_NODES) return;
    int c0 = lane * 2;

    unsigned int ow = *(const unsigned int*)&Hs[(size_t)node * 128 + c0];
    float accx = bf2f((unsigned short)(ow & 0xffffu));
    float accy = bf2f((unsigned short)(ow >> 16));

    int start = rowstart[node];
    int cnt   = counts[node];
    int end = start + cnt;
    int j = start;

    for (; j + 7 < end; j += 8) {
        int s0 = __builtin_nontemporal_load(&csr_src[j]);
        int s1 = __builtin_nontemporal_load(&csr_src[j + 1]);
        int s2 = __builtin_nontemporal_load(&csr_src[j + 2]);
        int s3 = __builtin_nontemporal_load(&csr_src[j + 3]);
        int s4 = __builtin_nontemporal_load(&csr_src[j + 4]);
        int s5 = __builtin_nontemporal_load(&csr_src[j + 5]);
        int s6 = __builtin_nontemporal_load(&csr_src[j + 6]);
        int s7 = __builtin_nontemporal_load(&csr_src[j + 7]);
        unsigned int w0 = *(const unsigned int*)&Hs[(size_t)s0 * 128 + c0];
        unsigned int w1 = *(const unsigned int*)&Hs[(size_t)s1 * 128 + c0];
        unsigned int w2 = *(const unsigned int*)&Hs[(size_t)s2 * 128 + c0];
        unsigned int w3 = *(const unsigned int*)&Hs[(size_t)s3 * 128 + c0];
        unsigned int w4 = *(const unsigned int*)&Hs[(size_t)s4 * 128 + c0];
        unsigned int w5 = *(const unsigned int*)&Hs[(size_t)s5 * 128 + c0];
        unsigned int w6 = *(const unsigned int*)&Hs[(size_t)s6 * 128 + c0];
        unsigned int w7 = *(const unsigned int*)&Hs[(size_t)s7 * 128 + c0];
        accx += ((bf2f((unsigned short)(w0 & 0xffffu)) + bf2f((unsigned short)(w1 & 0xffffu)))
               + (bf2f((unsigned short)(w2 & 0xffffu)) + bf2f((unsigned short)(w3 & 0xffffu))))
              + ((bf2f((unsigned short)(w4 & 0xffffu)) + bf2f((unsigned short)(w5 & 0xffffu)))
               + (bf2f((unsigned short)(w6 & 0xffffu)) + bf2f((unsigned short)(w7 & 0xffffu))));
        accy += ((bf2f((unsigned short)(w0 >> 16)) + bf2f((unsigned short)(w1 >> 16)))
               + (bf2f((unsigned short)(w2 >> 16)) + bf2f((unsigned short)(w3 >> 16))))
              + ((bf2f((unsigned short)(w4 >> 16)) + bf2f((unsigned short)(w5 >> 16)))
               + (bf2f((unsigned short)(w6 >> 16)) + bf2f((unsigned short)(w7 >> 16))));
    }
    for (; j + 1 < end; j += 2) {
        int s0 = __builtin_nontemporal_load(&csr_src[j]);
        int s1 = __builtin_nontemporal_load(&csr_src[j + 1]);
        unsigned int w0 = *(const unsigned int*)&Hs[(size_t)s0 * 128 + c0];
        unsigned int w1 = *(const unsigned int*)&Hs[(size_t)s1 * 128 + c0];
        accx += bf2f((unsigned short)(w0 & 0xffffu)) + bf2f((unsigned short)(w1 & 0xffffu));
        accy += bf2f((unsigned short)(w0 >> 16)) + bf2f((unsigned short)(w1 >> 16));
    }
    if (j < end) {
        int s0 = __builtin_nontemporal_load(&csr_src[j]);
        unsigned int w0 = *(const unsigned int*)&Hs[(size_t)s0 * 128 + c0];
        accx += bf2f((unsigned short)(w0 & 0xffffu));
        accy += bf2f((unsigned short)(w0 >> 16));
    }

    float dsi = dis[node];
    float2 bb = *(const float2*)&bias[c0];
    float rx = fmaxf(fmaf(accx, dsi, bb.x), 0.f);
    float ry = fmaxf(fmaf(accy, dsi, bb.y), 0.f);
    unsigned int pk = (unsigned int)f2bf(rx) | ((unsigned int)f2bf(ry) << 16);
    __builtin_nontemporal_store(pk, &OutU[(size_t)node * 64 + lane]);
}

// ---------------- Final: out = sigmoid(H @ Wr + br)*0.8 + 0.1 ----------------

__global__ __launch_bounds__(256) void final_kernel(const unsigned short* __restrict__ Hb,
                                                    const float* __restrict__ Wr,
                                                    const float* __restrict__ br,
                                                    float* __restrict__ out) {
    __shared__ float hs[16][132];
    __shared__ float ws[128][16];
    int tid = threadIdx.x;
    int rowBase = blockIdx.x * 16;
    {
#pragma unroll
        for (int q = 0; q < 4; q++) {
            int idx = q * 256 + tid;        // 0..1023: 16 rows x 64 bf16-pairs
            int r  = idx >> 6;
            int kp = (idx & 63) * 2;
            unsigned int w = *(const unsigned int*)&Hb[(size_t)(rowBase + r) * 128 + kp];
            hs[r][kp]     = bf2f((unsigned short)(w & 0xffffu));
            hs[r][kp + 1] = bf2f((unsigned short)(w >> 16));
        }
#pragma unroll
        for (int q = 0; q < 8; q++) {
            int idx = q * 256 + tid;
            ws[idx >> 4][idx & 15] = Wr[idx];
        }
    }
    __syncthreads();
    int row = tid >> 4;
    int c   = tid & 15;
    float acc = br[c];
#pragma unroll
    for (int k = 0; k < 128; k++)
        acc = fmaf(hs[row][k], ws[k][c], acc);
    int grow = rowBase + row;
    float sg = 1.f / (1.f + expf(-acc));
    out[(size_t)grow * 16 + c] = 0.8f * sg + 0.1f;
}

// ---------------- Launch ----------------

extern "C" void kernel_launch(void* const* d_in, const int* in_sizes, int n_in,
                              void* d_out, int out_size, void* d_ws, size_t ws_size,
                              hipStream_t stream) {
    const float* x  = (const float*)d_in[0];
    const int*   ei = (const int*)d_in[1];
    const int*   src = ei;
    const int*   dst = ei + N_EDGES;
    const float* W0 = (const float*)d_in[2];
    const float* b0 = (const float*)d_in[3];
    const float* W1 = (const float*)d_in[4];
    const float* b1 = (const float*)d_in[5];
    const float* W2 = (const float*)d_in[6];
    const float* b2 = (const float*)d_in[7];
    const float* Wr = (const float*)d_in[8];
    const float* br = (const float*)d_in[9];
    float* out = (float*)d_out;

    char* ws = (char*)d_ws;
    size_t off = 0;
    auto take = [&](size_t bytes) {
        char* p = ws + off;
        off += (bytes + 255) & ~(size_t)255;
        return p;
    };
    unsigned short* hAb      = (unsigned short*)take((size_t)N_NODES * 128 * 2); // agg out (bf16)
    unsigned short* hBs      = (unsigned short*)take((size_t)N_NODES * 128 * 2); // gemm out (bf16)
    unsigned short* Wt3      = (unsigned short*)take(3 * 128 * 128 * 2);         // W^T bf16 x3
    int*            counts   = (int*)take((size_t)N_NODES * 4);
    int*            rowstart = (int*)take((size_t)N_NODES * 4);
    float*          dis      = (float*)take((size_t)N_NODES * 4);
    int*            csr_src  = (int*)take((size_t)N_EDGES * 4);
    int*            pairs    = (int*)take((size_t)N_EDGES * 4);
    int*            hist     = (int*)take((size_t)EB * NBUCKET * 4);
    int*            blkoffT  = (int*)take((size_t)NBUCKET * EB * 4);
    int*            btotal   = (int*)take(1024 * 4);
    (void)ws_size; (void)in_sizes; (void)n_in; (void)out_size;

    // All weight conversions in one launch, up front.
    wconv3_kernel<<<384, 128, 0, stream>>>(W0, W1, W2, Wt3);

    // CSR build: no global atomics, line-local scatters, bucket scan inlined in LDS.
    hist_kernel<<<EB, 256, 0, stream>>>(dst, hist);
    scan_hist_kernel<<<NBUCKET, 256, 0, stream>>>(hist, blkoffT, btotal);
    scatter_kernel<<<EB, 256, 0, stream>>>(src, dst, blkoffT, btotal, pairs);
    build_csr_kernel<<<NBUCKET, 256, 0, stream>>>(pairs, btotal, rowstart, counts, dis, csr_src);

    const float* bl[3] = {b0, b1, b2};
    int gemmBlocks = (N_NODES + 63) / 64;   // 1563
    for (int l = 0; l < 3; l++) {
        const unsigned short* Wt = Wt3 + l * 16384;
        if (l == 0)
            gemm_mfma_kernel<true><<<gemmBlocks, 256, 0, stream>>>(x, Wt, dis, hBs);
        else
            gemm_mfma_kernel<false><<<gemmBlocks, 256, 0, stream>>>(hAb, Wt, dis, hBs);
        aggregate_kernel<<<N_NODES / 4, 256, 0, stream>>>(hBs, dis, rowstart, counts,
                                                          csr_src, bl[l], (unsigned int*)hAb);
    }
    final_kernel<<<N_NODES / 16, 256, 0, stream>>>(hAb, Wr, br, out);
}